// Round 7
// baseline (979.736 us; speedup 1.0000x reference)
//
#include <hip/hip_runtime.h>
#include <hip/hip_fp16.h>

#define N_NODES 100000
#define N_EDGES 50000
#define NNZ     3200000
#define D       32
#define NB      391                 // buckets of 256 nodes
#define P1_CHUNK 4096
#define P1_T     512
#define P1_BLKS  ((NNZ + P1_CHUNK - 1) / P1_CHUNK)   // 782

// ---------------------------------------------------------------------------
// kXh: X (f32) -> Xh (f16 pairs packed in u32) — halves gather traffic in k2
// ---------------------------------------------------------------------------
__global__ void kXh(const float* __restrict__ X, unsigned int* __restrict__ XhU) {
    int i = blockIdx.x * blockDim.x + threadIdx.x;
    if (i >= N_NODES * (D / 2)) return;
    float2 v = ((const float2*)X)[i];
    __half2 h = __floats2half2_rn(v.x, v.y);
    XhU[i] = *(const unsigned int*)&h;
}

// ---------------------------------------------------------------------------
// K0: fuse weights.  M1 = W1 @ W2b, c1 = b1 @ W2b, A2 = W2a @ W, c2 = b2 @ W
// ---------------------------------------------------------------------------
__global__ void k0_weights(const float* __restrict__ W1, const float* __restrict__ b1,
                           const float* __restrict__ W2, const float* __restrict__ b2,
                           const float* __restrict__ Ww,
                           float* __restrict__ M1, float* __restrict__ c1,
                           float* __restrict__ A2, float* __restrict__ c2) {
    int t = threadIdx.x;            // 1024 threads
    int k = t >> 5, dd = t & 31;
    float m = 0.f, a = 0.f;
#pragma unroll
    for (int j = 0; j < D; ++j) {
        m = fmaf(W1[k * D + j], W2[(D + j) * D + dd], m);   // W1 @ W2b
        a = fmaf(W2[k * D + j], Ww[j * D + dd], a);          // W2a @ W
    }
    M1[k * D + dd] = m;
    A2[k * D + dd] = a;
    if (k == 0) {
        float cc1 = 0.f, cc2 = 0.f;
#pragma unroll
        for (int j = 0; j < D; ++j) {
            cc1 = fmaf(b1[j], W2[(D + j) * D + dd], cc1);
            cc2 = fmaf(b2[j], Ww[j * D + dd], cc2);
        }
        c1[dd] = cc1;
        c2[dd] = cc2;
    }
}

// ---------------------------------------------------------------------------
// k_seg: seg[e] = lower_bound(edges, e), one thread per e (0..N_EDGES incl.)
// ---------------------------------------------------------------------------
__global__ void k_seg(const int* __restrict__ edges, int* __restrict__ seg) {
    int e = blockIdx.x * blockDim.x + threadIdx.x;
    if (e > N_EDGES) return;
    int lo = 0, hi = NNZ;
    while (lo < hi) { int mid = (lo + hi) >> 1; if (edges[mid] < e) lo = mid + 1; else hi = mid; }
    seg[e] = lo;
}

// ---------------------------------------------------------------------------
// p1h: global bucket histogram (LDS-staged)
// ---------------------------------------------------------------------------
__global__ void p1h(const int* __restrict__ vertex, unsigned int* __restrict__ bcnt) {
    __shared__ unsigned int h[NB];
    for (int i = threadIdx.x; i < NB; i += blockDim.x) h[i] = 0;
    __syncthreads();
    int i = blockIdx.x * blockDim.x + threadIdx.x;
    int stride = gridDim.x * blockDim.x;
    for (; i < NNZ; i += stride) atomicAdd(&h[((unsigned)vertex[i]) >> 8], 1u);
    __syncthreads();
    for (int j = threadIdx.x; j < NB; j += blockDim.x)
        if (h[j]) atomicAdd(&bcnt[j], h[j]);
}

// ---------------------------------------------------------------------------
// kscan: exclusive scan of the 391 bucket counts -> boff, bcur
// ---------------------------------------------------------------------------
__global__ void kscan(const unsigned int* __restrict__ bcnt,
                      unsigned int* __restrict__ boff, unsigned int* __restrict__ bcur) {
    __shared__ unsigned int s[512];
    int t = threadIdx.x;
    unsigned int v = (t < NB) ? bcnt[t] : 0;
    s[t] = v;
    __syncthreads();
    for (int off = 1; off < 512; off <<= 1) {
        unsigned int u = (t >= off) ? s[t - off] : 0;
        __syncthreads();
        s[t] += u;
        __syncthreads();
    }
    if (t < NB) { unsigned int ex = s[t] - v; boff[t] = ex; bcur[t] = ex; }
    if (t == 0) boff[NB] = (unsigned)NNZ;
}

// ---------------------------------------------------------------------------
// p1: block-level radix partition (race-free). Each block orders its 4096
// incidences by bucket in LDS, reserves global space with ONE atomic per
// bucket, then writes coalesced runs. plist entry = (e<<8) | (v & 255).
// ---------------------------------------------------------------------------
__global__ __launch_bounds__(P1_T) void p1(const int* __restrict__ vertex,
                                           const int* __restrict__ edges,
                                           unsigned int* __restrict__ bcur,
                                           unsigned int* __restrict__ plist) {
    __shared__ unsigned int cnt[NB], excl[NB], cursor[NB], gbase[NB];
    __shared__ unsigned int scanb[P1_T];
    __shared__ unsigned int obuf[P1_CHUNK];
    __shared__ unsigned short obb[P1_CHUNK];
    int t = threadIdx.x;
    int c0 = blockIdx.x * P1_CHUNK;
    int cend = min(c0 + P1_CHUNK, NNZ);

    for (int i = t; i < NB; i += P1_T) cnt[i] = 0;
    __syncthreads();
    for (int i = c0 + t; i < cend; i += P1_T)
        atomicAdd(&cnt[((unsigned)vertex[i]) >> 8], 1u);
    __syncthreads();

    unsigned int myc = (t < NB) ? cnt[t] : 0;
    scanb[t] = myc;
    __syncthreads();
    for (int off = 1; off < P1_T; off <<= 1) {
        unsigned int u = (t >= off) ? scanb[t - off] : 0;
        __syncthreads();
        scanb[t] += u;
        __syncthreads();
    }
    if (t < NB) {
        unsigned int ex = scanb[t] - myc;
        excl[t] = ex; cursor[t] = ex;
        gbase[t] = myc ? atomicAdd(&bcur[t], myc) : 0u;
    }
    __syncthreads();

    for (int i = c0 + t; i < cend; i += P1_T) {
        unsigned int v = (unsigned)vertex[i];
        unsigned int e = (unsigned)edges[i];
        unsigned int b = v >> 8;
        unsigned int p = atomicAdd(&cursor[b], 1u);
        obuf[p] = (e << 8) | (v & 255u);
        obb[p]  = (unsigned short)b;
    }
    __syncthreads();

    int csize = cend - c0;
    for (int j = t; j < csize; j += P1_T) {
        unsigned int b = obb[j];
        plist[gbase[b] + (j - excl[b])] = obuf[j];
    }
}

// ---------------------------------------------------------------------------
// K2 (R4-validated version): per-edge, one wave per edge.
//   Xe = sum_i a_i * Xh[v_i]   (f16 gather, 4x unrolled, 2 half-waves)
//   fe = Xe @ M1 + (sum a_i) * c1
//   write Fe[e] dense as packed f16 pairs (coalesced, no atomics)
// ---------------------------------------------------------------------------
__global__ void k2_edge(const unsigned int* __restrict__ XhU,
                        const float* __restrict__ atts,
                        const int* __restrict__ vertex,
                        const int* __restrict__ seg,
                        const float* __restrict__ M1,
                        const float* __restrict__ c1,
                        unsigned int* __restrict__ FeU) {
    __shared__ float Ms[D * D];
    __shared__ float cs[D];
    for (int i = threadIdx.x; i < D * D; i += blockDim.x) Ms[i] = M1[i];
    if (threadIdx.x < D) cs[threadIdx.x] = c1[threadIdx.x];
    __syncthreads();

    int wave = threadIdx.x >> 6;
    int lane = threadIdx.x & 63;
    int d    = lane & 31;
    int h    = lane >> 5;
    int e    = blockIdx.x * (blockDim.x >> 6) + wave;
    if (e >= N_EDGES) return;

    int start = seg[e];
    int end   = seg[e + 1];
    int hi16  = d >> 1, sel = d & 1;

    float acc0 = 0.f, acc1 = 0.f, acc2 = 0.f, acc3 = 0.f, sa = 0.f;
    int i = start + h;
    for (; i + 6 < end; i += 8) {
        int   v0 = vertex[i],     v1 = vertex[i + 2], v2 = vertex[i + 4], v3 = vertex[i + 6];
        float a0 = atts[i],       a1 = atts[i + 2],   a2 = atts[i + 4],   a3 = atts[i + 6];
        unsigned int w0 = XhU[v0 * 16 + hi16], w1 = XhU[v1 * 16 + hi16];
        unsigned int w2 = XhU[v2 * 16 + hi16], w3 = XhU[v3 * 16 + hi16];
        acc0 = fmaf(a0, __half2float(((const __half*)&w0)[sel]), acc0);
        acc1 = fmaf(a1, __half2float(((const __half*)&w1)[sel]), acc1);
        acc2 = fmaf(a2, __half2float(((const __half*)&w2)[sel]), acc2);
        acc3 = fmaf(a3, __half2float(((const __half*)&w3)[sel]), acc3);
        sa += (a0 + a1) + (a2 + a3);
    }
    for (; i < end; i += 2) {
        int v = vertex[i];
        float a = atts[i];
        unsigned int w = XhU[v * 16 + hi16];
        acc0 = fmaf(a, __half2float(((const __half*)&w)[sel]), acc0);
        sa += a;
    }
    float acc = (acc0 + acc1) + (acc2 + acc3);
    acc += __shfl(acc, lane ^ 32, 64);
    sa  += __shfl(sa,  lane ^ 32, 64);

    float fe = sa * cs[d];
#pragma unroll
    for (int k = 0; k < D; ++k) {
        float xk = __shfl(acc, k, 32);
        fe = fmaf(xk, Ms[k * D + d], fe);
    }

    float other = __shfl(fe, lane ^ 1, 64);
    float flo = sel ? other : fe;
    float fhi = sel ? fe : other;
    __half2 hv = __floats2half2_rn(flo, fhi);
    if (h == 0 && sel == 0) FeU[e * 16 + hi16] = *reinterpret_cast<unsigned int*>(&hv);
}

// ---------------------------------------------------------------------------
// p2: one 1024-thread block per 256-node bucket. Phase-separated 8x-unrolled
// inner loop: stage 8 plist entries -> issue 8 independent FeU row gathers ->
// drain 8 NATIVE LDS float atomics (unsafeAtomicAdd -> ds_add_f32, pipelined;
// plain atomicAdd(float*) expands to a ~230-cycle serial CAS loop — measured
// R4/R6). Then fused node epilogue:
//   out = 0.5*(deg*(X@A2+c2) + (Sf+X0)@W) + b
// ---------------------------------------------------------------------------
__global__ __launch_bounds__(1024) void p2(const unsigned int* __restrict__ plist,
                                           const unsigned int* __restrict__ FeU,
                                           const unsigned int* __restrict__ boff,
                                           const float* __restrict__ X,
                                           const float* __restrict__ X0,
                                           const float* __restrict__ A2,
                                           const float* __restrict__ c2,
                                           const float* __restrict__ Ww,
                                           const float* __restrict__ bw,
                                           float* __restrict__ out) {
    __shared__ float tile[256 * D];            // 32 KB
    __shared__ unsigned int degT[256];
    __shared__ float As[D * D], Ws[D * D], c2s[D], bws[D];
    int t = threadIdx.x;
    for (int i = t; i < D * D; i += 1024) { As[i] = A2[i]; Ws[i] = Ww[i]; }
    if (t < D) { c2s[t] = c2[t]; bws[t] = bw[t]; }
    for (int i = t; i < 256 * D; i += 1024) tile[i] = 0.f;
    if (t < 256) degT[t] = 0;
    __syncthreads();

    int b = blockIdx.x;
    int base = b << 8;
    int start = (int)boff[b], end = (int)boff[b + 1];
    int hw = t >> 5, d = t & 31;               // 32 half-waves
    int hi16 = d >> 1, sel = d & 1;

    int i = start + hw;
    // phase-separated unroll-8: loads first (8 outstanding), then native atomics
    for (; i + 224 < end; i += 256) {
        unsigned int e0 = plist[i],       e1 = plist[i + 32],  e2 = plist[i + 64],  e3 = plist[i + 96];
        unsigned int e4 = plist[i + 128], e5 = plist[i + 160], e6 = plist[i + 192], e7 = plist[i + 224];
        unsigned int w0 = FeU[(e0 >> 8) * 16 + hi16], w1 = FeU[(e1 >> 8) * 16 + hi16];
        unsigned int w2 = FeU[(e2 >> 8) * 16 + hi16], w3 = FeU[(e3 >> 8) * 16 + hi16];
        unsigned int w4 = FeU[(e4 >> 8) * 16 + hi16], w5 = FeU[(e5 >> 8) * 16 + hi16];
        unsigned int w6 = FeU[(e6 >> 8) * 16 + hi16], w7 = FeU[(e7 >> 8) * 16 + hi16];
        unsafeAtomicAdd(&tile[(e0 & 255u) * D + d], __half2float(((const __half*)&w0)[sel]));
        unsafeAtomicAdd(&tile[(e1 & 255u) * D + d], __half2float(((const __half*)&w1)[sel]));
        unsafeAtomicAdd(&tile[(e2 & 255u) * D + d], __half2float(((const __half*)&w2)[sel]));
        unsafeAtomicAdd(&tile[(e3 & 255u) * D + d], __half2float(((const __half*)&w3)[sel]));
        unsafeAtomicAdd(&tile[(e4 & 255u) * D + d], __half2float(((const __half*)&w4)[sel]));
        unsafeAtomicAdd(&tile[(e5 & 255u) * D + d], __half2float(((const __half*)&w5)[sel]));
        unsafeAtomicAdd(&tile[(e6 & 255u) * D + d], __half2float(((const __half*)&w6)[sel]));
        unsafeAtomicAdd(&tile[(e7 & 255u) * D + d], __half2float(((const __half*)&w7)[sel]));
        if (d == 0) {
            atomicAdd(&degT[e0 & 255u], 1u); atomicAdd(&degT[e1 & 255u], 1u);
            atomicAdd(&degT[e2 & 255u], 1u); atomicAdd(&degT[e3 & 255u], 1u);
            atomicAdd(&degT[e4 & 255u], 1u); atomicAdd(&degT[e5 & 255u], 1u);
            atomicAdd(&degT[e6 & 255u], 1u); atomicAdd(&degT[e7 & 255u], 1u);
        }
    }
    for (; i < end; i += 32) {
        unsigned int ent = plist[i];
        unsigned int w = FeU[(ent >> 8) * 16 + hi16];
        unsafeAtomicAdd(&tile[(ent & 255u) * D + d], __half2float(((const __half*)&w)[sel]));
        if (d == 0) atomicAdd(&degT[ent & 255u], 1u);
    }
    __syncthreads();

    // epilogue: 32 half-waves x 8 rows = 256 nodes
    for (int r = 0; r < 8; ++r) {
        int ln = r * 32 + hw;
        int node = base + ln;
        if (node >= N_NODES) continue;
        float x = X[node * D + d];
        float s1 = c2s[d];
#pragma unroll
        for (int k = 0; k < D; ++k) s1 = fmaf(__shfl(x, k, 32), As[k * D + d], s1);
        float tt = tile[ln * D + d] + X0[node * D + d];
        float s2 = 0.f;
#pragma unroll
        for (int k = 0; k < D; ++k) s2 = fmaf(__shfl(tt, k, 32), Ws[k * D + d], s2);
        out[node * D + d] = 0.5f * fmaf((float)degT[ln], s1, s2) + bws[d];
    }
}

// ---------------------------------------------------------------------------
extern "C" void kernel_launch(void* const* d_in, const int* in_sizes, int n_in,
                              void* d_out, int out_size, void* d_ws, size_t ws_size,
                              hipStream_t stream) {
    const float* X      = (const float*)d_in[0];
    const float* X0     = (const float*)d_in[1];
    const float* atts   = (const float*)d_in[2];
    const float* W1w    = (const float*)d_in[3];
    const float* W1b    = (const float*)d_in[4];
    const float* W2w    = (const float*)d_in[5];
    const float* W2b    = (const float*)d_in[6];
    const float* Ww     = (const float*)d_in[7];
    const float* Wb     = (const float*)d_in[8];
    const int*   vertex = (const int*)d_in[9];
    const int*   edges  = (const int*)d_in[10];
    float*       out    = (float*)d_out;

    char* ws = (char*)d_ws;
    unsigned int* FeU   = (unsigned int*)(ws);                 //  3,200,000 B
    unsigned int* plist = (unsigned int*)(ws + 3200000);       // 12,800,000 B
    unsigned int* XhU   = (unsigned int*)(ws + 16000000);      //  6,400,000 B
    int*          seg   = (int*)         (ws + 22400000);      //    200,004 B
    unsigned int* bcnt  = (unsigned int*)(ws + 22600256);      //      1,564 B
    unsigned int* boff  = (unsigned int*)(ws + 22602048);      //      1,568 B
    unsigned int* bcur  = (unsigned int*)(ws + 22603648);      //      1,564 B
    float*        M1    = (float*)       (ws + 22605312);      //      4,096 B
    float*        A2    = (float*)       (ws + 22609408);      //      4,096 B
    float*        c1    = (float*)       (ws + 22613504);      //        128 B
    float*        c2    = (float*)       (ws + 22613632);      //        128 B

    hipMemsetAsync(bcnt, 0, NB * sizeof(unsigned int), stream);

    kXh       <<<(N_NODES * 16 + 255) / 256, 256, 0, stream>>>(X, XhU);
    k0_weights<<<1, 1024, 0, stream>>>(W1w, W1b, W2w, W2b, Ww, M1, c1, A2, c2);
    k_seg     <<<(N_EDGES + 256) / 256, 256, 0, stream>>>(edges, seg);
    p1h       <<<1024, 256, 0, stream>>>(vertex, bcnt);
    kscan     <<<1, 512, 0, stream>>>(bcnt, boff, bcur);
    p1        <<<P1_BLKS, P1_T, 0, stream>>>(vertex, edges, bcur, plist);
    k2_edge   <<<(N_EDGES + 3) / 4, 256, 0, stream>>>(XhU, atts, vertex, seg, M1, c1, FeU);
    p2        <<<NB, 1024, 0, stream>>>(plist, FeU, boff, X, X0, A2, c2, Ww, Wb, out);
}

// Round 8
// 315.773 us; speedup vs baseline: 3.1027x; 3.1027x over previous
//
#include <hip/hip_runtime.h>
#include <hip/hip_fp16.h>

#define N_NODES 100000
#define N_EDGES 50000
#define NNZ     3200000
#define D       32
#define NB      391                 // buckets of 256 nodes
#define P1_CHUNK 4096
#define P1_T     512
#define P1_BLKS  ((NNZ + P1_CHUNK - 1) / P1_CHUNK)   // 782
#define P2_CAP  9216                // bucket capacity: mean 8192, ~11 sigma

// ---------------------------------------------------------------------------
// kXh: X (f32) -> Xh (f16 pairs packed in u32) — halves gather traffic in k2
// ---------------------------------------------------------------------------
__global__ void kXh(const float* __restrict__ X, unsigned int* __restrict__ XhU) {
    int i = blockIdx.x * blockDim.x + threadIdx.x;
    if (i >= N_NODES * (D / 2)) return;
    float2 v = ((const float2*)X)[i];
    __half2 h = __floats2half2_rn(v.x, v.y);
    XhU[i] = *(const unsigned int*)&h;
}

// ---------------------------------------------------------------------------
// K0: fuse weights.  M1 = W1 @ W2b, c1 = b1 @ W2b, A2 = W2a @ W, c2 = b2 @ W
// ---------------------------------------------------------------------------
__global__ void k0_weights(const float* __restrict__ W1, const float* __restrict__ b1,
                           const float* __restrict__ W2, const float* __restrict__ b2,
                           const float* __restrict__ Ww,
                           float* __restrict__ M1, float* __restrict__ c1,
                           float* __restrict__ A2, float* __restrict__ c2) {
    int t = threadIdx.x;            // 1024 threads
    int k = t >> 5, dd = t & 31;
    float m = 0.f, a = 0.f;
#pragma unroll
    for (int j = 0; j < D; ++j) {
        m = fmaf(W1[k * D + j], W2[(D + j) * D + dd], m);   // W1 @ W2b
        a = fmaf(W2[k * D + j], Ww[j * D + dd], a);          // W2a @ W
    }
    M1[k * D + dd] = m;
    A2[k * D + dd] = a;
    if (k == 0) {
        float cc1 = 0.f, cc2 = 0.f;
#pragma unroll
        for (int j = 0; j < D; ++j) {
            cc1 = fmaf(b1[j], W2[(D + j) * D + dd], cc1);
            cc2 = fmaf(b2[j], Ww[j * D + dd], cc2);
        }
        c1[dd] = cc1;
        c2[dd] = cc2;
    }
}

// ---------------------------------------------------------------------------
// k_seg: seg[e] = lower_bound(edges, e), one thread per e (0..N_EDGES incl.)
// ---------------------------------------------------------------------------
__global__ void k_seg(const int* __restrict__ edges, int* __restrict__ seg) {
    int e = blockIdx.x * blockDim.x + threadIdx.x;
    if (e > N_EDGES) return;
    int lo = 0, hi = NNZ;
    while (lo < hi) { int mid = (lo + hi) >> 1; if (edges[mid] < e) lo = mid + 1; else hi = mid; }
    seg[e] = lo;
}

// ---------------------------------------------------------------------------
// p1h: global bucket histogram (LDS-staged)
// ---------------------------------------------------------------------------
__global__ void p1h(const int* __restrict__ vertex, unsigned int* __restrict__ bcnt) {
    __shared__ unsigned int h[NB];
    for (int i = threadIdx.x; i < NB; i += blockDim.x) h[i] = 0;
    __syncthreads();
    int i = blockIdx.x * blockDim.x + threadIdx.x;
    int stride = gridDim.x * blockDim.x;
    for (; i < NNZ; i += stride) atomicAdd(&h[((unsigned)vertex[i]) >> 8], 1u);
    __syncthreads();
    for (int j = threadIdx.x; j < NB; j += blockDim.x)
        if (h[j]) atomicAdd(&bcnt[j], h[j]);
}

// ---------------------------------------------------------------------------
// kscan: exclusive scan of the 391 bucket counts -> boff, bcur
// ---------------------------------------------------------------------------
__global__ void kscan(const unsigned int* __restrict__ bcnt,
                      unsigned int* __restrict__ boff, unsigned int* __restrict__ bcur) {
    __shared__ unsigned int s[512];
    int t = threadIdx.x;
    unsigned int v = (t < NB) ? bcnt[t] : 0;
    s[t] = v;
    __syncthreads();
    for (int off = 1; off < 512; off <<= 1) {
        unsigned int u = (t >= off) ? s[t - off] : 0;
        __syncthreads();
        s[t] += u;
        __syncthreads();
    }
    if (t < NB) { unsigned int ex = s[t] - v; boff[t] = ex; bcur[t] = ex; }
    if (t == 0) boff[NB] = (unsigned)NNZ;
}

// ---------------------------------------------------------------------------
// p1: block-level radix partition (race-free). Each block orders its 4096
// incidences by bucket in LDS, reserves global space with ONE atomic per
// bucket, then writes coalesced runs. plist entry = (e<<8) | (v & 255).
// ---------------------------------------------------------------------------
__global__ __launch_bounds__(P1_T) void p1(const int* __restrict__ vertex,
                                           const int* __restrict__ edges,
                                           unsigned int* __restrict__ bcur,
                                           unsigned int* __restrict__ plist) {
    __shared__ unsigned int cnt[NB], excl[NB], cursor[NB], gbase[NB];
    __shared__ unsigned int scanb[P1_T];
    __shared__ unsigned int obuf[P1_CHUNK];
    __shared__ unsigned short obb[P1_CHUNK];
    int t = threadIdx.x;
    int c0 = blockIdx.x * P1_CHUNK;
    int cend = min(c0 + P1_CHUNK, NNZ);

    for (int i = t; i < NB; i += P1_T) cnt[i] = 0;
    __syncthreads();
    for (int i = c0 + t; i < cend; i += P1_T)
        atomicAdd(&cnt[((unsigned)vertex[i]) >> 8], 1u);
    __syncthreads();

    unsigned int myc = (t < NB) ? cnt[t] : 0;
    scanb[t] = myc;
    __syncthreads();
    for (int off = 1; off < P1_T; off <<= 1) {
        unsigned int u = (t >= off) ? scanb[t - off] : 0;
        __syncthreads();
        scanb[t] += u;
        __syncthreads();
    }
    if (t < NB) {
        unsigned int ex = scanb[t] - myc;
        excl[t] = ex; cursor[t] = ex;
        gbase[t] = myc ? atomicAdd(&bcur[t], myc) : 0u;
    }
    __syncthreads();

    for (int i = c0 + t; i < cend; i += P1_T) {
        unsigned int v = (unsigned)vertex[i];
        unsigned int e = (unsigned)edges[i];
        unsigned int b = v >> 8;
        unsigned int p = atomicAdd(&cursor[b], 1u);
        obuf[p] = (e << 8) | (v & 255u);
        obb[p]  = (unsigned short)b;
    }
    __syncthreads();

    int csize = cend - c0;
    for (int j = t; j < csize; j += P1_T) {
        unsigned int b = obb[j];
        plist[gbase[b] + (j - excl[b])] = obuf[j];
    }
}

// ---------------------------------------------------------------------------
// K2 (R4-validated version): per-edge, one wave per edge.
//   Xe = sum_i a_i * Xh[v_i]   (f16 gather, 4x unrolled, 2 half-waves)
//   fe = Xe @ M1 + (sum a_i) * c1
//   write Fe[e] dense as packed f16 pairs (coalesced, no atomics)
// ---------------------------------------------------------------------------
__global__ void k2_edge(const unsigned int* __restrict__ XhU,
                        const float* __restrict__ atts,
                        const int* __restrict__ vertex,
                        const int* __restrict__ seg,
                        const float* __restrict__ M1,
                        const float* __restrict__ c1,
                        unsigned int* __restrict__ FeU) {
    __shared__ float Ms[D * D];
    __shared__ float cs[D];
    for (int i = threadIdx.x; i < D * D; i += blockDim.x) Ms[i] = M1[i];
    if (threadIdx.x < D) cs[threadIdx.x] = c1[threadIdx.x];
    __syncthreads();

    int wave = threadIdx.x >> 6;
    int lane = threadIdx.x & 63;
    int d    = lane & 31;
    int h    = lane >> 5;
    int e    = blockIdx.x * (blockDim.x >> 6) + wave;
    if (e >= N_EDGES) return;

    int start = seg[e];
    int end   = seg[e + 1];
    int hi16  = d >> 1, sel = d & 1;

    float acc0 = 0.f, acc1 = 0.f, acc2 = 0.f, acc3 = 0.f, sa = 0.f;
    int i = start + h;
    for (; i + 6 < end; i += 8) {
        int   v0 = vertex[i],     v1 = vertex[i + 2], v2 = vertex[i + 4], v3 = vertex[i + 6];
        float a0 = atts[i],       a1 = atts[i + 2],   a2 = atts[i + 4],   a3 = atts[i + 6];
        unsigned int w0 = XhU[v0 * 16 + hi16], w1 = XhU[v1 * 16 + hi16];
        unsigned int w2 = XhU[v2 * 16 + hi16], w3 = XhU[v3 * 16 + hi16];
        acc0 = fmaf(a0, __half2float(((const __half*)&w0)[sel]), acc0);
        acc1 = fmaf(a1, __half2float(((const __half*)&w1)[sel]), acc1);
        acc2 = fmaf(a2, __half2float(((const __half*)&w2)[sel]), acc2);
        acc3 = fmaf(a3, __half2float(((const __half*)&w3)[sel]), acc3);
        sa += (a0 + a1) + (a2 + a3);
    }
    for (; i < end; i += 2) {
        int v = vertex[i];
        float a = atts[i];
        unsigned int w = XhU[v * 16 + hi16];
        acc0 = fmaf(a, __half2float(((const __half*)&w)[sel]), acc0);
        sa += a;
    }
    float acc = (acc0 + acc1) + (acc2 + acc3);
    acc += __shfl(acc, lane ^ 32, 64);
    sa  += __shfl(sa,  lane ^ 32, 64);

    float fe = sa * cs[d];
#pragma unroll
    for (int k = 0; k < D; ++k) {
        float xk = __shfl(acc, k, 32);
        fe = fmaf(xk, Ms[k * D + d], fe);
    }

    float other = __shfl(fe, lane ^ 1, 64);
    float flo = sel ? other : fe;
    float fhi = sel ? fe : other;
    __half2 hv = __floats2half2_rn(flo, fhi);
    if (h == 0 && sel == 0) FeU[e * 16 + hi16] = *reinterpret_cast<unsigned int*>(&hv);
}

// ---------------------------------------------------------------------------
// p2: one 1024-thread block per 256-node bucket. ZERO f32 atomics:
//   1) int histogram of local node (ent & 255)       [~8K int LDS atomics]
//   2) Hillis-Steele scan (256) -> offsets
//   3) int-cursor scatter: sbuf sorted by node        [~8K int LDS atomics]
//   4) each half-wave owns 8 nodes; contiguous entries -> register
//      accumulation of sf via unroll-4 independent FeU line gathers
//   5) fused per-node epilogue: out = 0.5*(deg*(X@A2+c2) + (sf+X0)@W) + b
// Rationale: R4/R6/R7 measured an LDS f32 atomic-RMW wall (~4.7 cy/lane-op/CU,
// invariant to ILP and wave count). Sorting with int atomics then gathering
// into registers removes the f32 RMW pipe from the path entirely.
// ---------------------------------------------------------------------------
__global__ __launch_bounds__(1024) void p2(const unsigned int* __restrict__ plist,
                                           const unsigned int* __restrict__ FeU,
                                           const unsigned int* __restrict__ boff,
                                           const float* __restrict__ X,
                                           const float* __restrict__ X0,
                                           const float* __restrict__ A2,
                                           const float* __restrict__ c2,
                                           const float* __restrict__ Ww,
                                           const float* __restrict__ bw,
                                           float* __restrict__ out) {
    __shared__ unsigned int sbuf[P2_CAP];      // 36,864 B (node-sorted entries)
    __shared__ unsigned int cnt[256];          // per-node counts
    __shared__ unsigned int pos[256];          // inclusive scan of cnt
    __shared__ unsigned int cursor[256];       // scatter cursors
    __shared__ float As[D * D], Ws[D * D], c2s[D], bws[D];
    int t = threadIdx.x;
    for (int i = t; i < D * D; i += 1024) { As[i] = A2[i]; Ws[i] = Ww[i]; }
    if (t < D) { c2s[t] = c2[t]; bws[t] = bw[t]; }
    if (t < 256) cnt[t] = 0;
    __syncthreads();

    int b = blockIdx.x;
    int base = b << 8;
    int start = (int)boff[b];
    int n = (int)boff[b + 1] - start;

    // 1) histogram by local node id
    for (int i = t; i < n; i += 1024)
        atomicAdd(&cnt[plist[start + i] & 255u], 1u);
    __syncthreads();

    // 2) inclusive scan of cnt into pos (Hillis-Steele, barriers unguarded)
    unsigned int v = (t < 256) ? cnt[t] : 0;
    if (t < 256) pos[t] = v;
    __syncthreads();
    for (int off = 1; off < 256; off <<= 1) {
        unsigned int u = 0;
        if (t < 256 && t >= off) u = pos[t - off];
        __syncthreads();
        if (t < 256) pos[t] += u;
        __syncthreads();
    }
    if (t < 256) cursor[t] = pos[t] - v;       // exclusive offset
    __syncthreads();

    // 3) scatter into sbuf sorted by node (second read of plist; L2-hot)
    for (int i = t; i < n; i += 1024) {
        unsigned int ent = plist[start + i];
        unsigned int p = atomicAdd(&cursor[ent & 255u], 1u);
        sbuf[p] = ent;
    }
    __syncthreads();

    // 4+5) half-wave hw owns nodes ln = r*32+hw; register accumulate + epilogue
    int hw = t >> 5, d = t & 31;
    int hi16 = d >> 1, sel = d & 1;
    for (int r = 0; r < 8; ++r) {
        int ln = r * 32 + hw;
        int node = base + ln;
        if (node >= N_NODES) continue;
        int deg = (int)cnt[ln];
        int st  = (int)pos[ln] - deg;

        float sf = 0.f;
        int k = 0;
        for (; k + 3 < deg; k += 4) {
            unsigned int e0 = sbuf[st + k] >> 8,     e1 = sbuf[st + k + 1] >> 8;
            unsigned int e2 = sbuf[st + k + 2] >> 8, e3 = sbuf[st + k + 3] >> 8;
            unsigned int w0 = FeU[e0 * 16 + hi16], w1 = FeU[e1 * 16 + hi16];
            unsigned int w2 = FeU[e2 * 16 + hi16], w3 = FeU[e3 * 16 + hi16];
            sf += __half2float(((const __half*)&w0)[sel]) + __half2float(((const __half*)&w1)[sel])
                + __half2float(((const __half*)&w2)[sel]) + __half2float(((const __half*)&w3)[sel]);
        }
        for (; k < deg; ++k) {
            unsigned int e0 = sbuf[st + k] >> 8;
            unsigned int w0 = FeU[e0 * 16 + hi16];
            sf += __half2float(((const __half*)&w0)[sel]);
        }

        float x = X[node * D + d];
        float s1 = c2s[d];
#pragma unroll
        for (int kk = 0; kk < D; ++kk) s1 = fmaf(__shfl(x, kk, 32), As[kk * D + d], s1);
        float tt = sf + X0[node * D + d];
        float s2 = 0.f;
#pragma unroll
        for (int kk = 0; kk < D; ++kk) s2 = fmaf(__shfl(tt, kk, 32), Ws[kk * D + d], s2);
        out[node * D + d] = 0.5f * fmaf((float)deg, s1, s2) + bws[d];
    }
}

// ---------------------------------------------------------------------------
extern "C" void kernel_launch(void* const* d_in, const int* in_sizes, int n_in,
                              void* d_out, int out_size, void* d_ws, size_t ws_size,
                              hipStream_t stream) {
    const float* X      = (const float*)d_in[0];
    const float* X0     = (const float*)d_in[1];
    const float* atts   = (const float*)d_in[2];
    const float* W1w    = (const float*)d_in[3];
    const float* W1b    = (const float*)d_in[4];
    const float* W2w    = (const float*)d_in[5];
    const float* W2b    = (const float*)d_in[6];
    const float* Ww     = (const float*)d_in[7];
    const float* Wb     = (const float*)d_in[8];
    const int*   vertex = (const int*)d_in[9];
    const int*   edges  = (const int*)d_in[10];
    float*       out    = (float*)d_out;

    char* ws = (char*)d_ws;
    unsigned int* FeU   = (unsigned int*)(ws);                 //  3,200,000 B
    unsigned int* plist = (unsigned int*)(ws + 3200000);       // 12,800,000 B
    unsigned int* XhU   = (unsigned int*)(ws + 16000000);      //  6,400,000 B
    int*          seg   = (int*)         (ws + 22400000);      //    200,004 B
    unsigned int* bcnt  = (unsigned int*)(ws + 22600256);      //      1,564 B
    unsigned int* boff  = (unsigned int*)(ws + 22602048);      //      1,568 B
    unsigned int* bcur  = (unsigned int*)(ws + 22603648);      //      1,564 B
    float*        M1    = (float*)       (ws + 22605312);      //      4,096 B
    float*        A2    = (float*)       (ws + 22609408);      //      4,096 B
    float*        c1    = (float*)       (ws + 22613504);      //        128 B
    float*        c2    = (float*)       (ws + 22613632);      //        128 B

    hipMemsetAsync(bcnt, 0, NB * sizeof(unsigned int), stream);

    kXh       <<<(N_NODES * 16 + 255) / 256, 256, 0, stream>>>(X, XhU);
    k0_weights<<<1, 1024, 0, stream>>>(W1w, W1b, W2w, W2b, Ww, M1, c1, A2, c2);
    k_seg     <<<(N_EDGES + 256) / 256, 256, 0, stream>>>(edges, seg);
    p1h       <<<1024, 256, 0, stream>>>(vertex, bcnt);
    kscan     <<<1, 512, 0, stream>>>(bcnt, boff, bcur);
    p1        <<<P1_BLKS, P1_T, 0, stream>>>(vertex, edges, bcur, plist);
    k2_edge   <<<(N_EDGES + 3) / 4, 256, 0, stream>>>(XhU, atts, vertex, seg, M1, c1, FeU);
    p2        <<<NB, 1024, 0, stream>>>(plist, FeU, boff, X, X0, A2, c2, Ww, Wb, out);
}